// Round 7
// baseline (13014.891 us; speedup 1.0000x reference)
//
#include <hip/hip_runtime.h>
#include <stdint.h>

#define BB 16
#define TT 1000
#define SZ 896
#define HF 448
#define NC 112            // compute WGs (pure matvec)
#define NWG 240           // 112 compute + 128 sampler (16 x (4 coarse + 4 fine))
#define LDS_FLOATS 30112
#define LDS_BYTES (LDS_FLOATS * 4)

typedef float f32x4 __attribute__((ext_vector_type(4)));
typedef float f32x2 __attribute__((ext_vector_type(2)));

// Persistent device-global state.
__device__ float g_hid[2 * BB * SZ];     // double-buffered hidden [2][16][896]
__device__ float g_hpc4[BB * HF * 4];    // coarse hp rows [16][448][4] = {h_r,h_u,h_e,pad}
__device__ float g_hpf4[BB * HF * 4];    // fine hp rows   [16][448][4]
__device__ uint32_t g_cdone[NC * 16];    // compute flags: value = t+1 (hp_t ready)
__device__ uint32_t g_chrdy[BB * 16];    // ch_t published: value = t+1
__device__ uint32_t g_fhrdy[BB * 16];    // fh_t published: value = t+1
__device__ unsigned long long g_afl[BB * 4 * 8];  // coarse candidates {score, (t+1)<<16|bin<<8}
__device__ unsigned long long g_bfl[BB * 4 * 8];  // fine candidates

// ---- pipelined coherent (L2-bypassing) loads/stores ----
__device__ __forceinline__ void cload4x4(const float* p, f32x4& a0, f32x4& a1, f32x4& a2, f32x4& a3) {
  asm volatile(
      "global_load_dwordx4 %0, %4, off sc0 sc1\n\t"
      "global_load_dwordx4 %1, %4, off offset:16 sc0 sc1\n\t"
      "global_load_dwordx4 %2, %4, off offset:32 sc0 sc1\n\t"
      "global_load_dwordx4 %3, %4, off offset:48 sc0 sc1\n\t"
      "s_waitcnt vmcnt(0)"
      : "=&v"(a0), "=&v"(a1), "=&v"(a2), "=&v"(a3) : "v"(p) : "memory");
}
__device__ __forceinline__ f32x4 cload1x4(const float* p) {
  f32x4 a;
  asm volatile("global_load_dwordx4 %0, %1, off sc0 sc1\n\ts_waitcnt vmcnt(0)"
               : "=&v"(a) : "v"(p) : "memory");
  return a;
}
__device__ __forceinline__ void cstore4d(float* p, f32x4 v) {
  asm volatile("global_store_dwordx4 %0, %1, off sc0 sc1\n\ts_waitcnt vmcnt(0)"
               :: "v"(p), "v"(v) : "memory");
}
__device__ __forceinline__ void cstore1u_nw(uint32_t* p, uint32_t v) {
  asm volatile("global_store_dword %0, %1, off sc0 sc1" :: "v"(p), "v"(v) : "memory");
}
__device__ __forceinline__ void cstore2u_nw(unsigned long long* p, f32x2 v) {
  asm volatile("global_store_dwordx2 %0, %1, off sc0 sc1" :: "v"(p), "v"(v) : "memory");
}

__device__ __forceinline__ void waitFlag(uint32_t* f, uint32_t target) {
  while (__hip_atomic_load(f, __ATOMIC_RELAXED, __HIP_MEMORY_SCOPE_AGENT) < target)
    __builtin_amdgcn_s_sleep(1);
}
__device__ __forceinline__ void waitFlagA(uint32_t* f, uint32_t target) {
  while (__hip_atomic_load(f, __ATOMIC_RELAXED, __HIP_MEMORY_SCOPE_AGENT) < target)
    __builtin_amdgcn_s_sleep(2);
}
__device__ __forceinline__ unsigned long long waitFlag64(unsigned long long* f, uint32_t tag) {
  unsigned long long u;
  while ((uint32_t)((u = __hip_atomic_load(f, __ATOMIC_RELAXED, __HIP_MEMORY_SCOPE_AGENT)) >> 48) < tag)
    __builtin_amdgcn_s_sleep(1);
  return u;
}

__device__ __forceinline__ uint32_t rotl32(uint32_t v, int d) {
  return (v << d) | (v >> (32 - d));
}

// JAX threefry2x32 (20 rounds), bit-exact
__device__ __forceinline__ uint2 tf2(uint32_t k0, uint32_t k1, uint32_t x0, uint32_t x1) {
  const uint32_t k2 = k0 ^ k1 ^ 0x1BD11BDAu;
  x0 += k0; x1 += k1;
  x0 += x1; x1 = rotl32(x1,13); x1 ^= x0;
  x0 += x1; x1 = rotl32(x1,15); x1 ^= x0;
  x0 += x1; x1 = rotl32(x1,26); x1 ^= x0;
  x0 += x1; x1 = rotl32(x1, 6); x1 ^= x0;
  x0 += k1; x1 += k2 + 1u;
  x0 += x1; x1 = rotl32(x1,17); x1 ^= x0;
  x0 += x1; x1 = rotl32(x1,29); x1 ^= x0;
  x0 += x1; x1 = rotl32(x1,16); x1 ^= x0;
  x0 += x1; x1 = rotl32(x1,24); x1 ^= x0;
  x0 += k2; x1 += k0 + 2u;
  x0 += x1; x1 = rotl32(x1,13); x1 ^= x0;
  x0 += x1; x1 = rotl32(x1,15); x1 ^= x0;
  x0 += x1; x1 = rotl32(x1,26); x1 ^= x0;
  x0 += x1; x1 = rotl32(x1, 6); x1 ^= x0;
  x0 += k0; x1 += k1 + 3u;
  x0 += x1; x1 = rotl32(x1,17); x1 ^= x0;
  x0 += x1; x1 = rotl32(x1,29); x1 ^= x0;
  x0 += x1; x1 = rotl32(x1,16); x1 ^= x0;
  x0 += x1; x1 = rotl32(x1,24); x1 ^= x0;
  x0 += k1; x1 += k2 + 4u;
  x0 += x1; x1 = rotl32(x1,13); x1 ^= x0;
  x0 += x1; x1 = rotl32(x1,15); x1 ^= x0;
  x0 += x1; x1 = rotl32(x1,26); x1 ^= x0;
  x0 += x1; x1 = rotl32(x1, 6); x1 ^= x0;
  x0 += k2; x1 += k0 + 5u;
  return make_uint2(x0, x1);
}

__device__ __forceinline__ float gumbel_bits(uint32_t bits) {
  const float tiny = 1.17549435e-38f;
  float f = __uint_as_float((bits >> 9) | 0x3f800000u) - 1.0f;
  float u = fmaxf(tiny, f + tiny);
  return -logf(-logf(u));
}

// 64-bin logit partials from LDS-resident weight slice wlds[448][65] (padded).
// Wave w covers K in [56w, 56w+56); lane = local bin. Bit-identical chain order.
__device__ __forceinline__ void logits64(const float* __restrict__ wlds,
                                         const float* __restrict__ vec,
                                         float* __restrict__ plds, int tid) {
  const int w = tid >> 6, lane = tid & 63;
  float a = 0.f;
  const float* wp = wlds + (56 * w) * 65 + lane;
  const float* cp = vec + 56 * w;
#pragma unroll 8
  for (int ii = 0; ii < 56; ++ii)
    a = fmaf(cp[ii], wp[ii * 65], a);
  plds[(w << 6) | lane] = a;
}

__global__ __launch_bounds__(256, 1) void wavernn_init() {
  const int idx = blockIdx.x * 256 + threadIdx.x;   // 112 x 256 = 28672
  g_hid[idx] = 0.f;
  if (idx < NC * 16) g_cdone[idx] = 0u;
  if (idx < BB * 16) { g_chrdy[idx] = 0u; g_fhrdy[idx] = 0u; }
  if (idx < BB * 4 * 8) { g_afl[idx] = 0ull; g_bfl[idx] = 0ull; }
}

__global__ __launch_bounds__(512, 1) void wavernn_main(
    const float* __restrict__ cond, const float* __restrict__ gib,
    const float* __restrict__ W_h,  const float* __restrict__ b_h,
    const float* __restrict__ W_ci, const float* __restrict__ b_ci,
    const float* __restrict__ W_fi, const float* __restrict__ b_fi,
    const float* __restrict__ W_bc, const float* __restrict__ b_bc,
    const float* __restrict__ W_bf, const float* __restrict__ b_bf,
    float* __restrict__ out) {
  extern __shared__ float smem[];
  const int wg = blockIdx.x, tid = threadIdx.x;

  if (wg < NC) {
    // ================= compute role: pure matvec, 8 waves x 1 channel-row task ==========
    float* hlds = smem;                       // [16][900]
    const int wave = tid >> 6, lane = tid & 63;
    const int l32 = lane >> 1, b2 = lane & 1;
    const int tp = wave >> 2;                 // 0=coarse rows, 1=fine rows
    const int chan = (wg << 2) | (wave & 3);  // 0..447
    const int rb = tp ? (HF + chan) : chan;
    float4 w[3][7];
    float brow[3];
#pragma unroll
    for (int r = 0; r < 3; ++r) {
      const int row = r * SZ + rb;
      brow[r] = b_h[row];
#pragma unroll
      for (int m = 0; m < 7; ++m)
        w[r][m] = *(const float4*)&W_h[(size_t)row * SZ + 4 * l32 + 128 * m];
    }
    const int r16 = tid & 15, c28 = tid >> 4;   // staging coords (c28<28 active)

    for (int t = 0; t < TT; ++t) {
      const int p = (t & 1) ^ 1;   // hidden_{t-1} buffer
      // ---- wait ch_{t-1}; stage coarse half; coarse-K matvec
      if (tid < BB) waitFlagA(&g_chrdy[tid * 16], (uint32_t)t);
      __syncthreads();
      if (c28 < 28) {
        const float* src = g_hid + (size_t)p * BB * SZ + r16 * SZ + c28 * 16;
        f32x4 a0, a1, a2, a3;
        cload4x4(src, a0, a1, a2, a3);
        float* dst = hlds + r16 * 900 + c28 * 16;
        *(f32x4*)(dst) = a0; *(f32x4*)(dst + 4) = a1;
        *(f32x4*)(dst + 8) = a2; *(f32x4*)(dst + 12) = a3;
      }
      __syncthreads();
      float acc[3][8];
#pragma unroll
      for (int r = 0; r < 3; ++r)
#pragma unroll
        for (int i = 0; i < 8; ++i) acc[r][i] = 0.f;
#pragma unroll
      for (int i = 0; i < 8; ++i) {
        const int b = b2 + 2 * i;
        const float* hb = hlds + b * 900 + 4 * l32;
        const float4 h0 = *(const float4*)(hb);
        const float4 h1 = *(const float4*)(hb + 128);
        const float4 h2 = *(const float4*)(hb + 256);
#pragma unroll
        for (int r = 0; r < 3; ++r) {
          float s = acc[r][i];
          s = fmaf(w[r][0].x, h0.x, s); s = fmaf(w[r][0].y, h0.y, s);
          s = fmaf(w[r][0].z, h0.z, s); s = fmaf(w[r][0].w, h0.w, s);
          s = fmaf(w[r][1].x, h1.x, s); s = fmaf(w[r][1].y, h1.y, s);
          s = fmaf(w[r][1].z, h1.z, s); s = fmaf(w[r][1].w, h1.w, s);
          s = fmaf(w[r][2].x, h2.x, s); s = fmaf(w[r][2].y, h2.y, s);
          s = fmaf(w[r][2].z, h2.z, s); s = fmaf(w[r][2].w, h2.w, s);
          acc[r][i] = s;
        }
        if (l32 < 16) {
          const float4 h3 = *(const float4*)(hb + 384);
#pragma unroll
          for (int r = 0; r < 3; ++r) {
            float s = acc[r][i];
            s = fmaf(w[r][3].x, h3.x, s); s = fmaf(w[r][3].y, h3.y, s);
            s = fmaf(w[r][3].z, h3.z, s); s = fmaf(w[r][3].w, h3.w, s);
            acc[r][i] = s;
          }
        }
      }
      // ---- wait fh_{t-1}; stage fine half; finish matvec
      if (tid < BB) waitFlag(&g_fhrdy[tid * 16], (uint32_t)t);
      __syncthreads();
      if (c28 < 28) {
        const float* src = g_hid + (size_t)p * BB * SZ + r16 * SZ + HF + c28 * 16;
        f32x4 a0, a1, a2, a3;
        cload4x4(src, a0, a1, a2, a3);
        float* dst = hlds + r16 * 900 + HF + c28 * 16;
        *(f32x4*)(dst) = a0; *(f32x4*)(dst + 4) = a1;
        *(f32x4*)(dst + 8) = a2; *(f32x4*)(dst + 12) = a3;
      }
      __syncthreads();
#pragma unroll
      for (int i = 0; i < 8; ++i) {
        const int b = b2 + 2 * i;
        const float* hb = hlds + b * 900 + 4 * l32;
        if (l32 >= 16) {
          const float4 h3 = *(const float4*)(hb + 384);
#pragma unroll
          for (int r = 0; r < 3; ++r) {
            float s = acc[r][i];
            s = fmaf(w[r][3].x, h3.x, s); s = fmaf(w[r][3].y, h3.y, s);
            s = fmaf(w[r][3].z, h3.z, s); s = fmaf(w[r][3].w, h3.w, s);
            acc[r][i] = s;
          }
        }
        const float4 h4 = *(const float4*)(hb + 512);
        const float4 h5 = *(const float4*)(hb + 640);
        const float4 h6 = *(const float4*)(hb + 768);
#pragma unroll
        for (int r = 0; r < 3; ++r) {
          float s = acc[r][i];
          s = fmaf(w[r][4].x, h4.x, s); s = fmaf(w[r][4].y, h4.y, s);
          s = fmaf(w[r][4].z, h4.z, s); s = fmaf(w[r][4].w, h4.w, s);
          s = fmaf(w[r][5].x, h5.x, s); s = fmaf(w[r][5].y, h5.y, s);
          s = fmaf(w[r][5].z, h5.z, s); s = fmaf(w[r][5].w, h5.w, s);
          s = fmaf(w[r][6].x, h6.x, s); s = fmaf(w[r][6].y, h6.y, s);
          s = fmaf(w[r][6].z, h6.z, s); s = fmaf(w[r][6].w, h6.w, s);
          acc[r][i] = s;
        }
      }
#pragma unroll
      for (int r = 0; r < 3; ++r)
#pragma unroll
        for (int i = 0; i < 8; ++i) {
          float v = acc[r][i];
          v += __shfl_xor(v, 2);
          v += __shfl_xor(v, 4);
          v += __shfl_xor(v, 8);
          v += __shfl_xor(v, 16);
          v += __shfl_xor(v, 32);
          acc[r][i] = v;
        }
      // ---- publish hp rows (coarse AND fine) + flag; no gate math here
      if (lane < 16) {
        const int bb = lane, i = lane >> 1;
        f32x4 hv;
        hv.x = acc[0][i] + brow[0];
        hv.y = acc[1][i] + brow[1];
        hv.z = acc[2][i] + brow[2];
        hv.w = 0.f;
        float* dst = (tp ? g_hpf4 : g_hpc4) + ((size_t)bb * HF + chan) * 4;
        cstore4d(dst, hv);
      }
      __syncthreads();
      if (tid == 0) cstore1u_nw(&g_cdone[wg * 16], (uint32_t)(t + 1));
    }
  } else {
    // ================= sampler role: 8 WGs/batch = 4 coarse + 4 fine, gates + logits =====
    const int swg = wg - NC;            // 0..127
    const int b = swg >> 3;
    const int role = (swg >> 2) & 1;    // 0 = coarse, 1 = fine
    const int k = swg & 3;              // 64-bin slice
    float* wlds = smem;                 // [448][65] padded weight slice
    float* vlds = smem + 29120;         // [448] state (ch or fh)
    float* plds = smem + 29568;         // [8][64] K-partials
    float* aS = smem + 30080;           // [4]
    int*   aI = (int*)(smem + 30084);   // [4]
    float* bS = smem + 30088;           // [4]
    int*   bI = (int*)(smem + 30092);   // [4]
    {
      const float* Wm = role ? W_bf : W_bc;
      for (int i = tid; i < HF * 64; i += 512) {
        const int bn = i / HF, kk = i - bn * HF;
        wlds[kk * 65 + bn] = Wm[(size_t)(64 * k + bn) * HF + kk];
      }
    }
    const float* bias = role ? b_bf : b_bc;
    // per-thread gate params (channel = tid < 448)
    float gw0[3], gw1[3], gw2[3], gbe[3], pc[3];
    if (tid < HF) {
      if (role == 0) {
#pragma unroll
        for (int g = 0; g < 3; ++g) {
          const int rr = g * HF + tid;
          gw0[g] = W_ci[2 * rr]; gw1[g] = W_ci[2 * rr + 1]; gw2[g] = 0.f;
          gbe[g] = b_ci[rr] + gib[g * SZ + tid];
          pc[g] = cond[(((size_t)b * TT) * 3 + g) * SZ + tid];
        }
      } else {
#pragma unroll
        for (int g = 0; g < 3; ++g) {
          const int rr = g * HF + tid;
          gw0[g] = W_fi[3 * rr]; gw1[g] = W_fi[3 * rr + 1]; gw2[g] = W_fi[3 * rr + 2];
          gbe[g] = b_fi[rr] + gib[g * SZ + HF + tid];
          pc[g] = cond[(((size_t)b * TT) * 3 + g) * SZ + HF + tid];
        }
      }
      vlds[tid] = 0.f;    // state_{-1} = 0
    }
    __syncthreads();
    float cvO = -1.f;     // cv_{t-1}
    float fvO = -1.f;     // fv_{t-1} (FS tracks own; CS derives from bfl)

    for (int t = 0; t < TT; ++t) {
      const int q = t & 1;
      const uint2 kf = tf2(0u, 1u, 0u, (uint32_t)t);
      float gub = 0.f;
      if (tid < 64) {
        const uint2 kk = role ? tf2(kf.x, kf.y, 0u, 1u) : tf2(kf.x, kf.y, 0u, 0u);
        const uint2 o = tf2(kk.x, kk.y, 0u, (uint32_t)(b * 256 + 64 * k + tid));
        gub = gumbel_bits(o.x ^ o.y);
      }
      if (role == 0) {
        // ---------------- coarse WG: gates -> publish ch -> logits -> afl exchange ------
        if (t > 0 && tid >= 452 && tid < 456) {   // sf_{t-1} candidates (long since published)
          const unsigned long long u = waitFlag64(&g_bfl[(b * 4 + (tid - 452)) * 8], (uint32_t)t);
          bS[tid - 452] = __uint_as_float((uint32_t)u);
          bI[tid - 452] = (int)((u >> 40) & 255u);
        }
        if (tid < NC) waitFlag(&g_cdone[tid * 16], (uint32_t)(t + 1));
        __syncthreads();
        float fvv = -1.f;
        if (t > 0) {
          float ms = bS[0]; int sf = bI[0];
#pragma unroll
          for (int m = 1; m < 4; ++m) {
            const float so = bS[m]; const int io = bI[m];
            if (so > ms || (so == ms && io < sf)) { ms = so; sf = io; }
          }
          fvv = (float)sf / 127.5f - 1.0f;
        }
        if (tid < HF) {
          const f32x4 hp = cload1x4(&g_hpc4[((size_t)b * HF + tid) * 4]);
          const float cp0 = fmaf(cvO, gw0[0], fmaf(fvv, gw1[0], gbe[0])) + pc[0];
          const float cp1 = fmaf(cvO, gw0[1], fmaf(fvv, gw1[1], gbe[1])) + pc[1];
          const float cp2 = fmaf(cvO, gw0[2], fmaf(fvv, gw1[2], gbe[2])) + pc[2];
          const float rg = 1.f / (1.f + expf(-(cp0 + hp.x)));
          const float ug = 1.f / (1.f + expf(-(cp1 + hp.y)));
          const float eg = tanhf(fmaf(rg, hp.z, cp2));
          vlds[tid] = ug * vlds[tid] + (1.f - ug) * eg;
        }
        __syncthreads();
        if (k == 0) {
          if (tid < 112)
            cstore4d(&g_hid[(size_t)q * BB * SZ + b * SZ + 4 * tid], *(f32x4*)&vlds[4 * tid]);
          __syncthreads();
          if (tid == 0) cstore1u_nw(&g_chrdy[b * 16], (uint32_t)(t + 1));
        }
        logits64(wlds, vlds, plds, tid);
        __syncthreads();
        if (tid < 64) {
          const float p0 = plds[tid],       p1 = plds[64 + tid];
          const float p2 = plds[128 + tid], p3 = plds[192 + tid];
          const float p4 = plds[256 + tid], p5 = plds[320 + tid];
          const float p6 = plds[384 + tid], p7 = plds[448 + tid];
          const float sum = ((p0 + p1) + (p2 + p3)) + ((p4 + p5) + (p6 + p7));
          float s = (sum + bias[64 * k + tid]) + gub;
          int idx = 64 * k + tid;
#pragma unroll
          for (int m = 1; m < 64; m <<= 1) {
            const float so = __shfl_xor(s, m);
            const int io = __shfl_xor(idx, m);
            if (so > s || (so == s && io < idx)) { s = so; idx = io; }
          }
          if (tid == 0) {
            f32x2 v; v.x = s;
            v.y = __uint_as_float(((uint32_t)(t + 1) << 16) | ((uint32_t)idx << 8));
            cstore2u_nw(&g_afl[(b * 4 + k) * 8], v);
          }
        }
        if (tid >= 448 && tid < 452) {
          const unsigned long long u = waitFlag64(&g_afl[(b * 4 + (tid - 448)) * 8], (uint32_t)(t + 1));
          aS[tid - 448] = __uint_as_float((uint32_t)u);
          aI[tid - 448] = (int)((u >> 40) & 255u);
        }
        __syncthreads();
        {
          float ms = aS[0]; int sc = aI[0];
#pragma unroll
          for (int m = 1; m < 4; ++m) {
            const float so = aS[m]; const int io = aI[m];
            if (so > ms || (so == ms && io < sc)) { ms = so; sc = io; }
          }
          cvO = (float)sc / 127.5f - 1.0f;
          if (k == 0 && tid == 0) out[b * TT + t] = (float)sc;
        }
        if (tid < HF && t + 1 < TT) {
#pragma unroll
          for (int g = 0; g < 3; ++g)
            pc[g] = cond[(((size_t)b * TT + (t + 1)) * 3 + g) * SZ + tid];
        }
      } else {
        // ---------------- fine WG: sc -> gates -> publish fh -> logits -> bfl exchange ---
        if (tid < NC) waitFlag(&g_cdone[tid * 16], (uint32_t)(t + 1));
        __syncthreads();
        f32x4 hp = {0.f, 0.f, 0.f, 0.f};
        if (tid < HF) hp = cload1x4(&g_hpf4[((size_t)b * HF + tid) * 4]);
        if (tid >= 448 && tid < 452) {
          const unsigned long long u = waitFlag64(&g_afl[(b * 4 + (tid - 448)) * 8], (uint32_t)(t + 1));
          aS[tid - 448] = __uint_as_float((uint32_t)u);
          aI[tid - 448] = (int)((u >> 40) & 255u);
        }
        __syncthreads();
        float ms = aS[0]; int sc = aI[0];
#pragma unroll
        for (int m = 1; m < 4; ++m) {
          const float so = aS[m]; const int io = aI[m];
          if (so > ms || (so == ms && io < sc)) { ms = so; sc = io; }
        }
        const float cvNew = (float)sc / 127.5f - 1.0f;
        if (tid < HF) {
          const float fp0 = fmaf(cvO, gw0[0], fmaf(fvO, gw1[0], fmaf(cvNew, gw2[0], gbe[0]))) + pc[0];
          const float fp1 = fmaf(cvO, gw0[1], fmaf(fvO, gw1[1], fmaf(cvNew, gw2[1], gbe[1]))) + pc[1];
          const float fp2 = fmaf(cvO, gw0[2], fmaf(fvO, gw1[2], fmaf(cvNew, gw2[2], gbe[2]))) + pc[2];
          const float rg = 1.f / (1.f + expf(-(fp0 + hp.x)));
          const float ug = 1.f / (1.f + expf(-(fp1 + hp.y)));
          const float eg = tanhf(fmaf(rg, hp.z, fp2));
          vlds[tid] = ug * vlds[tid] + (1.f - ug) * eg;
        }
        __syncthreads();
        if (k == 0) {
          if (tid < 112)
            cstore4d(&g_hid[(size_t)q * BB * SZ + b * SZ + HF + 4 * tid], *(f32x4*)&vlds[4 * tid]);
          __syncthreads();
          if (tid == 0) cstore1u_nw(&g_fhrdy[b * 16], (uint32_t)(t + 1));
        }
        logits64(wlds, vlds, plds, tid);
        __syncthreads();
        if (tid < 64) {
          const float p0 = plds[tid],       p1 = plds[64 + tid];
          const float p2 = plds[128 + tid], p3 = plds[192 + tid];
          const float p4 = plds[256 + tid], p5 = plds[320 + tid];
          const float p6 = plds[384 + tid], p7 = plds[448 + tid];
          const float sum = ((p0 + p1) + (p2 + p3)) + ((p4 + p5) + (p6 + p7));
          float s = (sum + bias[64 * k + tid]) + gub;
          int idx = 64 * k + tid;
#pragma unroll
          for (int m = 1; m < 64; m <<= 1) {
            const float so = __shfl_xor(s, m);
            const int io = __shfl_xor(idx, m);
            if (so > s || (so == s && io < idx)) { s = so; idx = io; }
          }
          if (tid == 0) {
            f32x2 v; v.x = s;
            v.y = __uint_as_float(((uint32_t)(t + 1) << 16) | ((uint32_t)idx << 8));
            cstore2u_nw(&g_bfl[(b * 4 + k) * 8], v);
          }
        }
        if (tid >= 448 && tid < 452) {
          const unsigned long long u = waitFlag64(&g_bfl[(b * 4 + (tid - 448)) * 8], (uint32_t)(t + 1));
          bS[tid - 448] = __uint_as_float((uint32_t)u);
          bI[tid - 448] = (int)((u >> 40) & 255u);
        }
        __syncthreads();
        {
          float msf = bS[0]; int sf = bI[0];
#pragma unroll
          for (int m = 1; m < 4; ++m) {
            const float so = bS[m]; const int io = bI[m];
            if (so > msf || (so == msf && io < sf)) { msf = so; sf = io; }
          }
          fvO = (float)sf / 127.5f - 1.0f;
          if (k == 0 && tid == 0) out[BB * TT + b * TT + t] = (float)sf;
        }
        cvO = cvNew;
        if (tid < HF && t + 1 < TT) {
#pragma unroll
          for (int g = 0; g < 3; ++g)
            pc[g] = cond[(((size_t)b * TT + (t + 1)) * 3 + g) * SZ + HF + tid];
        }
      }
    }
    // final hidden from LDS state
    if (k == 0 && tid < HF) {
      if (role == 0) out[2 * BB * TT + (size_t)b * SZ + tid] = vlds[tid];
      else           out[2 * BB * TT + (size_t)b * SZ + HF + tid] = vlds[tid];
    }
  }
}

extern "C" void kernel_launch(void* const* d_in, const int* in_sizes, int n_in,
                              void* d_out, int out_size, void* d_ws, size_t ws_size,
                              hipStream_t stream) {
  (void)in_sizes; (void)n_in; (void)out_size; (void)d_ws; (void)ws_size;
  const float* cond = (const float*)d_in[0];
  const float* gib  = (const float*)d_in[1];
  const float* W_h  = (const float*)d_in[2];
  const float* b_h  = (const float*)d_in[3];
  const float* W_ci = (const float*)d_in[4];
  const float* b_ci = (const float*)d_in[5];
  const float* W_fi = (const float*)d_in[6];
  const float* b_fi = (const float*)d_in[7];
  const float* W_bc = (const float*)d_in[8];
  const float* b_bc = (const float*)d_in[9];
  const float* W_bf = (const float*)d_in[10];
  const float* b_bf = (const float*)d_in[11];
  float* out = (float*)d_out;
  hipFuncSetAttribute((const void*)wavernn_main,
                      hipFuncAttributeMaxDynamicSharedMemorySize, LDS_BYTES);
  wavernn_init<<<NC, 256, 0, stream>>>();
  wavernn_main<<<NWG, 512, LDS_BYTES, stream>>>(cond, gib, W_h, b_h, W_ci, b_ci,
                                                W_fi, b_fi, W_bc, b_bc, W_bf, b_bf, out);
}